// Round 1
// baseline (275.574 us; speedup 1.0000x reference)
//
#include <hip/hip_runtime.h>

// Point transformer block, B=1 N=512 D=256 H=8 HD=32 CD=3 HID=682.
// Strategy: never materialize rel (N,N,3) / rel_value (N,N,D).
//   P*[i,e] = coords[i] @ W1[e,:]  ->  hidden[i,j,e] = silu(P[i,e]+b[e]-P[j,e])
//   context2[h,i,:] = (sum_j w[h,i,j] * hidden_v[i,j,:]) @ rv2_w(h-slice)^T + rv2_b
// rb2_b cancels in softmax (constant over j).

#define NN 512
#define DD 256
#define HH 8
#define HDD 32
#define HIDN 682
#define QKSCALE 0.17677669529663687f

// workspace offsets (in floats); total 1,596,416 floats = 6.39 MB
#define OFF_XN    0
#define OFF_PBT   131072   // [256][512]  coords@rb1 (transposed, no bias)
#define OFF_PVR   262144   // [512][256]  coords@rv1 (row-major, no bias)
#define OFF_RV2T  393216   // [256][256]  rv2_w transposed: rv2T[e][c]=rv2_w[c][e]
#define OFF_RB2T  458752   // [256][8]    rb2_w transposed
#define OFF_QKV   460800   // [512][768]
#define OFF_KT    854016   // [256][512]  k transposed: kT[c][j]
#define OFF_X2    985088   // [512][256]  x + attn_out
#define OFF_XN2   1116160  // [512][256]  LN2(x2)
#define OFF_H1    1247232  // [512][682]  swiglu hidden

static __device__ __forceinline__ float wredSum(float v){
#pragma unroll
  for (int o = 1; o < 64; o <<= 1) v += __shfl_xor(v, o, 64);
  return v;
}
static __device__ __forceinline__ float wredMax(float v){
#pragma unroll
  for (int o = 1; o < 64; o <<= 1) v = fmaxf(v, __shfl_xor(v, o, 64));
  return v;
}
static __device__ __forceinline__ float fsilu(float x){
  // x * sigmoid(x); rcp approx (~1ulp) is fine at fp32 output tolerance
  return x * __builtin_amdgcn_rcpf(1.0f + __expf(-x));
}

// ---------------- K1: LN1 + coord projections + weight transposes ----------
__global__ __launch_bounds__(256) void k1_prep(
    const float* __restrict__ x, const float* __restrict__ coords,
    const float* __restrict__ ln1_w, const float* __restrict__ ln1_b,
    const float* __restrict__ rb1_w, const float* __restrict__ rv1_w,
    const float* __restrict__ rv2_w, const float* __restrict__ rb2_w,
    float* __restrict__ ws)
{
  __shared__ float r4[4];
  const int i = blockIdx.x, t = threadIdx.x, lane = t & 63, wid = t >> 6;
  const float v = x[i*DD + t];
  float s = wredSum(v);
  if (lane == 0) r4[wid] = s;
  __syncthreads();
  const float mu = (r4[0]+r4[1]+r4[2]+r4[3]) * (1.0f/DD);
  const float d = v - mu;
  float s2 = wredSum(d*d);
  __syncthreads();
  if (lane == 0) r4[wid] = s2;
  __syncthreads();
  const float var = (r4[0]+r4[1]+r4[2]+r4[3]) * (1.0f/DD);
  const float rstd = rsqrtf(var + 1e-5f);
  ws[OFF_XN + i*DD + t] = d*rstd*ln1_w[t] + ln1_b[t];

  const float c0 = coords[i*3+0], c1 = coords[i*3+1], c2 = coords[i*3+2];
  ws[OFF_PBT + t*NN + i] = c0*rb1_w[t*3+0] + c1*rb1_w[t*3+1] + c2*rb1_w[t*3+2];
  ws[OFF_PVR + i*DD + t] = c0*rv1_w[t*3+0] + c1*rv1_w[t*3+1] + c2*rv1_w[t*3+2];
  if (i < DD) { // block index doubles as channel e for one-time transposes
    ws[OFF_RV2T + i*DD + t] = rv2_w[t*DD + i];
    if (t < HH) ws[OFF_RB2T + i*HH + t] = rb2_w[t*DD + i];
  }
}

// ---------------- K2: QKV GEMM [512,256]@[256,768]^T, + kT ----------------
__global__ __launch_bounds__(256) void k2_qkv(
    const float* __restrict__ qkv_w, const float* __restrict__ qkv_b,
    float* __restrict__ ws)
{
  __shared__ float xr[8*DD];
  const int i0 = blockIdx.x*8, rep = blockIdx.y, t = threadIdx.x;
#pragma unroll
  for (int r = 0; r < 8; ++r) xr[r*DD + t] = ws[OFF_XN + (i0+r)*DD + t];
  __syncthreads();
  const int o = rep*DD + t;
  float acc[8];
  const float b = qkv_b[o];
#pragma unroll
  for (int r = 0; r < 8; ++r) acc[r] = b;
  const float* wrow = qkv_w + (size_t)o*DD;
  for (int dd = 0; dd < DD; dd += 4) {
    const float4 w4 = *(const float4*)(wrow + dd);
#pragma unroll
    for (int r = 0; r < 8; ++r) {
      const float4 xv = *(const float4*)&xr[r*DD + dd];
      acc[r] += xv.x*w4.x + xv.y*w4.y + xv.z*w4.z + xv.w*w4.w;
    }
  }
#pragma unroll
  for (int r = 0; r < 8; ++r) ws[OFF_QKV + (size_t)(i0+r)*768 + o] = acc[r];
  if (rep == 1) { // k channel t, rows i0..i0+7 -> transposed copy
#pragma unroll
    for (int r = 0; r < 8; ++r) ws[OFF_KT + t*NN + i0 + r] = acc[r];
  }
}

// ---------------- K3: fused scores+softmax+context+residual+LN2 -----------
// one block per query row i; 512 threads (8 waves); ~61KB LDS -> 2 blocks/CU
__global__ __launch_bounds__(512) void k3_attn(
    const float* __restrict__ x,
    const float* __restrict__ rb1_b, const float* __restrict__ rv1_b,
    const float* __restrict__ rv2_b,
    const float* __restrict__ ln2_w, const float* __restrict__ ln2_b,
    float* __restrict__ ws)
{
  __shared__ __align__(16) float pbI[DD];
  __shared__ __align__(16) float pvI[DD];
  __shared__ __align__(16) float qI[DD];
  __shared__ __align__(16) float rb2T_l[DD*HH];
  __shared__ __align__(16) float swl[HH*513];     // scores, padded (bank-safe)
  __shared__ __align__(16) float wTl[NN*HH];      // softmax weights, [j][h]
  __shared__ __align__(16) float Gh[2][HH*257];   // G half-partials, padded
  __shared__ __align__(16) float c1h[2*DD];
  __shared__ float red[8];

  const int i = blockIdx.x, t = threadIdx.x, lane = t & 63, wid = t >> 6;
  const float* PbT = ws + OFF_PBT;
  const float* PvR = ws + OFF_PVR;
  const float* qkv = ws + OFF_QKV;
  const float* kT  = ws + OFF_KT;

  if (t < DD) {
    pbI[t] = PbT[t*NN + i] + rb1_b[t];   // bias folded into the i-role
    pvI[t] = PvR[i*DD + t] + rv1_b[t];
    qI[t]  = qkv[i*768 + t];
  }
  for (int idx = t; idx < DD*HH; idx += 512) rb2T_l[idx] = ws[OFF_RB2T + idx];
  __syncthreads();

  // ---- Phase A: scores[h][j] = qk/sqrt(hd) + rel_bias  (thread = j) ----
  {
    const int j = t;
    float bias[HH] = {0,0,0,0,0,0,0,0};
    for (int e = 0; e < DD; ++e) {
      const float s = fsilu(pbI[e] - PbT[e*NN + j]);   // coalesced global
      float wv[8];
      *(float4*)&wv[0] = *(const float4*)&rb2T_l[e*HH];
      *(float4*)&wv[4] = *(const float4*)&rb2T_l[e*HH + 4];
#pragma unroll
      for (int h = 0; h < HH; ++h) bias[h] += wv[h]*s;
    }
#pragma unroll
    for (int h = 0; h < HH; ++h) {
      float a = 0.f;
#pragma unroll
      for (int d = 0; d < HDD; ++d) a += qI[h*HDD + d] * kT[(h*HDD + d)*NN + j];
      swl[h*513 + j] = a*QKSCALE + bias[h];            // rb2_b cancels in softmax
    }
  }
  __syncthreads();

  // ---- softmax: wave wid owns head wid ----
  {
    const int h = wid;
    float v[8]; float m = -3.4e38f;
#pragma unroll
    for (int r = 0; r < 8; ++r) { v[r] = swl[h*513 + lane + r*64]; m = fmaxf(m, v[r]); }
    m = wredMax(m);
    float sum = 0.f;
#pragma unroll
    for (int r = 0; r < 8; ++r) { v[r] = __expf(v[r] - m); sum += v[r]; }
    sum = wredSum(sum);
    const float rz = __builtin_amdgcn_rcpf(sum);
#pragma unroll
    for (int r = 0; r < 8; ++r) wTl[(lane + r*64)*HH + h] = v[r]*rz;
  }
  __syncthreads();

  // ---- Phase B: G[h][e] = sum_j w[h][j] * silu(pvI[e]-Pv[j][e]) ----
  // thread = (e, j-half); coalesced PvR reads; no cross-lane reductions
  {
    const int e = t & 255, half = t >> 8;
    const float pv = pvI[e];
    float acc[HH] = {0,0,0,0,0,0,0,0};
    const int j0 = half*256;
    for (int jj = 0; jj < 256; ++jj) {
      const int j = j0 + jj;
      const float s = fsilu(pv - PvR[j*DD + e]);
      float wv[8];
      *(float4*)&wv[0] = *(const float4*)&wTl[j*HH];
      *(float4*)&wv[4] = *(const float4*)&wTl[j*HH + 4];
#pragma unroll
      for (int h = 0; h < HH; ++h) acc[h] += wv[h]*s;
    }
#pragma unroll
    for (int h = 0; h < HH; ++h) Gh[half][h*257 + e] = acc[h];
  }

  // ---- Phase C: context1[c] = sum_j w[h(c)][j] * v[j][c] ----
  {
    const int c = t & 255, half = t >> 8, h = c >> 5;
    float a1 = 0.f;
    const int j0 = half*256;
    for (int jj = 0; jj < 256; ++jj) {
      const int j = j0 + jj;
      a1 += wTl[j*HH + h] * qkv[j*768 + 512 + c];      // coalesced v reads
    }
    c1h[half*DD + c] = a1;
  }
  __syncthreads();

  // ---- Phase D: context2 = G @ rv2^T + rv2_b; residual + LN2 ----
  float x2v = 0.f;
  if (t < DD) {
    const int c = t, h = c >> 5;
    float ctx2 = rv2_b[c];                             // exact: sum_j w = 1
    for (int e = 0; e < DD; ++e) {
      const float g = Gh[0][h*257 + e] + Gh[1][h*257 + e];
      ctx2 += g * ws[OFF_RV2T + e*DD + c];             // coalesced
    }
    const float attn = c1h[c] + c1h[DD + c] + ctx2;
    x2v = x[i*DD + c] + attn;
  }
  float s = wredSum(t < DD ? x2v : 0.f);
  if (lane == 0) red[wid] = s;
  __syncthreads();
  const float mu = (red[0]+red[1]+red[2]+red[3]) * (1.0f/DD);
  const float dd_ = (t < DD) ? (x2v - mu) : 0.f;
  float s2 = wredSum(dd_*dd_);
  __syncthreads();
  if (lane == 0) red[wid] = s2;
  __syncthreads();
  const float var = (red[0]+red[1]+red[2]+red[3]) * (1.0f/DD);
  const float rstd = rsqrtf(var + 1e-5f);
  if (t < DD) {
    ws[OFF_X2  + i*DD + t] = x2v;
    ws[OFF_XN2 + i*DD + t] = (x2v - mu)*rstd*ln2_w[t] + ln2_b[t];
  }
}

// ---------------- K4: SwiGLU up-projections ----------------
__global__ __launch_bounds__(256) void k4_ffn1(
    const float* __restrict__ w1, const float* __restrict__ b1,
    const float* __restrict__ w2, const float* __restrict__ b2,
    float* __restrict__ ws)
{
  __shared__ float xr[8*DD];
  const int i0 = blockIdx.x*8, rep = blockIdx.y, t = threadIdx.x;
#pragma unroll
  for (int r = 0; r < 8; ++r) xr[r*DD + t] = ws[OFF_XN2 + (i0+r)*DD + t];
  __syncthreads();
  const int o = rep*DD + t;
  if (o >= HIDN) return;   // after the only sync
  float a1[8], a2[8];
  const float bb1 = b1[o], bb2 = b2[o];
#pragma unroll
  for (int r = 0; r < 8; ++r) { a1[r] = bb1; a2[r] = bb2; }
  const float* w1r = w1 + (size_t)o*DD;
  const float* w2r = w2 + (size_t)o*DD;
  for (int dd = 0; dd < DD; dd += 4) {
    const float4 u = *(const float4*)(w1r + dd);
    const float4 w = *(const float4*)(w2r + dd);
#pragma unroll
    for (int r = 0; r < 8; ++r) {
      const float4 xv = *(const float4*)&xr[r*DD + dd];
      a1[r] += xv.x*u.x + xv.y*u.y + xv.z*u.z + xv.w*u.w;
      a2[r] += xv.x*w.x + xv.y*w.y + xv.z*w.z + xv.w*w.w;
    }
  }
#pragma unroll
  for (int r = 0; r < 8; ++r)
    ws[OFF_H1 + (size_t)(i0+r)*HIDN + o] = fsilu(a1[r]) * a2[r];
}

// ---------------- K5: down-projection + residual ----------------
__global__ __launch_bounds__(256) void k5_ffn2(
    const float* __restrict__ w3, const float* __restrict__ b3,
    float* __restrict__ out, const float* __restrict__ ws)
{
  __shared__ float hr[4*HIDN];
  const int i0 = blockIdx.x*4, t = threadIdx.x;
#pragma unroll
  for (int r = 0; r < 4; ++r)
    for (int e = t; e < HIDN; e += 256) hr[r*HIDN + e] = ws[OFF_H1 + (size_t)(i0+r)*HIDN + e];
  __syncthreads();
  const int c = t;
  float acc[4];
  const float bb = b3[c];
#pragma unroll
  for (int r = 0; r < 4; ++r) acc[r] = bb + ws[OFF_X2 + (i0+r)*DD + c];
  const float* w3r = w3 + (size_t)c*HIDN;
  for (int e = 0; e < HIDN; e += 2) {   // 682 even; 8B-aligned float2
    const float2 w = *(const float2*)(w3r + e);
#pragma unroll
    for (int r = 0; r < 4; ++r) acc[r] += hr[r*HIDN + e]*w.x + hr[r*HIDN + e + 1]*w.y;
  }
#pragma unroll
  for (int r = 0; r < 4; ++r) out[(i0+r)*DD + c] = acc[r];
}

extern "C" void kernel_launch(void* const* d_in, const int* in_sizes, int n_in,
                              void* d_out, int out_size, void* d_ws, size_t ws_size,
                              hipStream_t stream) {
  (void)in_sizes; (void)n_in; (void)out_size; (void)ws_size;
  const float* x      = (const float*)d_in[0];
  const float* coords = (const float*)d_in[1];
  const float* ln1_w  = (const float*)d_in[2];
  const float* ln1_b  = (const float*)d_in[3];
  const float* ln2_w  = (const float*)d_in[4];
  const float* ln2_b  = (const float*)d_in[5];
  const float* qkv_w  = (const float*)d_in[6];
  const float* qkv_b  = (const float*)d_in[7];
  const float* rb1_w  = (const float*)d_in[8];
  const float* rb1_b  = (const float*)d_in[9];
  const float* rb2_w  = (const float*)d_in[10];
  /* d_in[11] = rb2_b: constant over j -> cancels in softmax */
  const float* rv1_w  = (const float*)d_in[12];
  const float* rv1_b  = (const float*)d_in[13];
  const float* rv2_w  = (const float*)d_in[14];
  const float* rv2_b  = (const float*)d_in[15];
  const float* ffn_w1 = (const float*)d_in[16];
  const float* ffn_b1 = (const float*)d_in[17];
  const float* ffn_w2 = (const float*)d_in[18];
  const float* ffn_b2 = (const float*)d_in[19];
  const float* ffn_w3 = (const float*)d_in[20];
  const float* ffn_b3 = (const float*)d_in[21];
  float* ws  = (float*)d_ws;
  float* out = (float*)d_out;

  k1_prep<<<NN, DD, 0, stream>>>(x, coords, ln1_w, ln1_b, rb1_w, rv1_w, rv2_w, rb2_w, ws);
  k2_qkv<<<dim3(NN/8, 3), DD, 0, stream>>>(qkv_w, qkv_b, ws);
  k3_attn<<<NN, 512, 0, stream>>>(x, rb1_b, rv1_b, rv2_b, ln2_w, ln2_b, ws);
  k4_ffn1<<<dim3(NN/8, 3), DD, 0, stream>>>(ffn_w1, ffn_b1, ffn_w2, ffn_b2, ws);
  k5_ffn2<<<NN/4, DD, 0, stream>>>(ffn_w3, ffn_b3, out, ws);
}